// Round 3
// baseline (1170.138 us; speedup 1.0000x reference)
//
#include <hip/hip_runtime.h>
#include <cstdint>

#define N_NODES 49152
#define DIM 512
#define NH 8
#define DHEAD 64
#define NE 131072
#define ETOT (NE + N_NODES)   /* 180224 */
#define NLAYERS 5

typedef short short8 __attribute__((ext_vector_type(8)));
typedef float floatx4 __attribute__((ext_vector_type(4)));

__device__ __forceinline__ float bf2f(unsigned short v) {
  union { unsigned int u; float f; } x; x.u = ((unsigned int)v) << 16; return x.f;
}
__device__ __forceinline__ unsigned short f2bf(float f) {
  union { float f; unsigned int u; } x; x.f = f;
  unsigned int r = x.u + 0x7fffu + ((x.u >> 16) & 1u);
  return (unsigned short)(r >> 16);
}

// ---------------- x: fp32 -> bf16 ----------------
__global__ __launch_bounds__(256) void convert_x_r3(const float* __restrict__ xf, unsigned short* __restrict__ xb)
{
  const size_t i = ((size_t)blockIdx.x * 256 + threadIdx.x) * 8;
  const float4 a = *(const float4*)&xf[i];
  const float4 b = *(const float4*)&xf[i + 4];
  unsigned int ov[4];
  ov[0] = (unsigned int)f2bf(a.x) | ((unsigned int)f2bf(a.y) << 16);
  ov[1] = (unsigned int)f2bf(a.z) | ((unsigned int)f2bf(a.w) << 16);
  ov[2] = (unsigned int)f2bf(b.x) | ((unsigned int)f2bf(b.y) << 16);
  ov[3] = (unsigned int)f2bf(b.z) | ((unsigned int)f2bf(b.w) << 16);
  *(uint4*)&xb[i] = *(const uint4*)ov;
}

// ---------------- W transpose + convert: WT[l][n][k] = bf16(Ws[l][k][n]) ----------------
__global__ void transpose_w_r3(const float* __restrict__ Ws, unsigned short* __restrict__ WT)
{
  __shared__ float tile[32][33];
  const int l  = blockIdx.z;
  const int nt = blockIdx.x * 32, kt = blockIdx.y * 32;
  const int tx = threadIdx.x & 31, ty = threadIdx.x >> 5;   // 256 threads
  #pragma unroll
  for (int r = 0; r < 32; r += 8)
    tile[ty + r][tx] = Ws[(size_t)l*DIM*DIM + (size_t)(kt + ty + r)*DIM + nt + tx];
  __syncthreads();
  #pragma unroll
  for (int r = 0; r < 32; r += 8)
    WT[(size_t)l*DIM*DIM + (size_t)(nt + ty + r)*DIM + kt + tx] = f2bf(tile[tx][ty + r]);
}

// ---------------- edge index canonicalize (auto-detect int64 vs int32) ----------------
__global__ void repack_edges_r3(const int* __restrict__ raw, int* __restrict__ eidx)
{
  const int i = blockIdx.x * 256 + threadIdx.x;    // 2*NE threads
  // If source data is int64 (little-endian, values < 2^31), every odd int32 is 0.
  bool is64 = true;
  #pragma unroll
  for (int j = 0; j < 16; j++) is64 = is64 && (raw[2*j + 1] == 0);
  int v;
  if (is64) v = (int)((const long long*)raw)[i];
  else      v = raw[i];
  eidx[i] = v;
}

// ---------------- CSR build ----------------
__global__ void init_counts_r3(int* __restrict__ counts) {
  counts[blockIdx.x * 256 + threadIdx.x] = 1;    // self-loop
}
__global__ void hist_dst_r3(const int* __restrict__ eidx, int* __restrict__ counts) {
  const int i = blockIdx.x * 256 + threadIdx.x;  // NE threads
  atomicAdd(&counts[eidx[NE + i]], 1);
}
__global__ void scan_kernel_r3(const int* __restrict__ counts, int* __restrict__ offs, int* __restrict__ cursor)
{
  __shared__ int tot[1024];
  const int t = threadIdx.x;
  const int base = t * 48;                       // N_NODES = 1024*48
  int s = 0;
  for (int i = 0; i < 48; i++) s += counts[base + i];
  tot[t] = s;
  __syncthreads();
  for (int o = 1; o < 1024; o <<= 1) {
    int v = (t >= o) ? tot[t - o] : 0;
    __syncthreads();
    tot[t] += v;
    __syncthreads();
  }
  int run = tot[t] - s;
  for (int i = 0; i < 48; i++) {
    offs[base + i] = run;
    cursor[base + i] = run;
    run += counts[base + i];
  }
  if (t == 1023) offs[N_NODES] = tot[1023];
}
__global__ void scatter_edges_r3(const int* __restrict__ eidx, int* __restrict__ cursor, int* __restrict__ csrc)
{
  const int i = blockIdx.x * 256 + threadIdx.x;  // ETOT threads
  int s, d;
  if (i < NE) { s = eidx[i]; d = eidx[NE + i]; }
  else        { s = i - NE; d = s; }
  const int pos = atomicAdd(&cursor[d], 1);
  csrc[pos] = s;
}

// ---------------- GEMM: C[M,512] = A[M,512] @ BT[512,512]^T (bf16, MFMA) ----------------
__global__ __launch_bounds__(256) void gemm_bt_r3(const unsigned short* __restrict__ A,
                                                  const unsigned short* __restrict__ BT,
                                                  unsigned short* __restrict__ C)
{
  __shared__ unsigned short As[128 * 64];
  __shared__ unsigned short Bs[128 * 64];
  const int m0 = blockIdx.x * 128;
  const int n0 = blockIdx.y * 128;
  const int tid = threadIdx.x;
  const int wv = tid >> 6, lane = tid & 63;
  const int wr = (wv >> 1) * 64, wc = (wv & 1) * 64;
  const int q = lane >> 4, c16 = lane & 15;

  floatx4 acc[4][4] = {};

  for (int k0 = 0; k0 < DIM; k0 += 64) {
    #pragma unroll
    for (int p = 0; p < 4; p++) {
      const int idx = (p * 256 + tid) * 8;    // element index within 128x64 tile
      const int row = idx >> 6, col = idx & 63;
      *(uint4*)&As[idx] = *(const uint4*)&A [(size_t)(m0 + row) * DIM + k0 + col];
      *(uint4*)&Bs[idx] = *(const uint4*)&BT[(size_t)(n0 + row) * DIM + k0 + col];
    }
    __syncthreads();
    #pragma unroll
    for (int kk = 0; kk < 64; kk += 32) {
      short8 aF[4], bF[4];
      #pragma unroll
      for (int mt = 0; mt < 4; mt++)
        aF[mt] = *(const short8*)&As[(wr + mt*16 + c16) * 64 + kk + q*8];
      #pragma unroll
      for (int nt = 0; nt < 4; nt++)
        bF[nt] = *(const short8*)&Bs[(wc + nt*16 + c16) * 64 + kk + q*8];
      #pragma unroll
      for (int mt = 0; mt < 4; mt++)
        #pragma unroll
        for (int nt = 0; nt < 4; nt++)
          acc[mt][nt] = __builtin_amdgcn_mfma_f32_16x16x32_bf16(aF[mt], bF[nt], acc[mt][nt], 0, 0, 0);
    }
    __syncthreads();
  }
  // C/D layout (verified m89/m91): col = lane&15, row = (lane>>4)*4 + reg
  #pragma unroll
  for (int mt = 0; mt < 4; mt++) {
    #pragma unroll
    for (int nt = 0; nt < 4; nt++) {
      const int col = n0 + wc + nt*16 + c16;
      #pragma unroll
      for (int r = 0; r < 4; r++) {
        const int row = m0 + wr + mt*16 + q*4 + r;
        C[(size_t)row * DIM + col] = f2bf(acc[mt][nt][r]);
      }
    }
  }
}

// ---------------- attention logits: als/ald[n,h] = sum_d h[n,h,d]*a[h,d] ----------------
__global__ __launch_bounds__(256) void attn_logits_r3(const unsigned short* __restrict__ Hm,
    const float* __restrict__ asrc, const float* __restrict__ adst,
    float* __restrict__ als, float* __restrict__ ald)
{
  const int wv = threadIdx.x >> 6, lane = threadIdx.x & 63;
  const int node = blockIdx.x * 4 + wv;
  const int hd = lane >> 3;
  const uint4 hv = *(const uint4*)&Hm[(size_t)node * DIM + lane * 8];
  const unsigned int* hp = (const unsigned int*)&hv;
  const float4 sA = ((const float4*)(asrc + (size_t)lane * 8))[0];
  const float4 sB = ((const float4*)(asrc + (size_t)lane * 8))[1];
  const float4 dA = ((const float4*)(adst + (size_t)lane * 8))[0];
  const float4 dB = ((const float4*)(adst + (size_t)lane * 8))[1];
  const float sarr[8] = {sA.x, sA.y, sA.z, sA.w, sB.x, sB.y, sB.z, sB.w};
  const float darr[8] = {dA.x, dA.y, dA.z, dA.w, dB.x, dB.y, dB.z, dB.w};
  float ss = 0.f, sd = 0.f;
  #pragma unroll
  for (int i = 0; i < 4; i++) {
    const float h0 = bf2f((unsigned short)(hp[i] & 0xffffu));
    const float h1 = bf2f((unsigned short)(hp[i] >> 16));
    ss += h0 * sarr[2*i] + h1 * sarr[2*i + 1];
    sd += h0 * darr[2*i] + h1 * darr[2*i + 1];
  }
  #pragma unroll
  for (int msk = 1; msk <= 4; msk <<= 1) {
    ss += __shfl_xor(ss, msk, 64);
    sd += __shfl_xor(sd, msk, 64);
  }
  if ((lane & 7) == 0) {
    als[node * NH + hd] = ss;
    ald[node * NH + hd] = sd;
  }
}

// ---------------- GAT aggregate (softmax over CSR segment) + bias ----------------
__global__ __launch_bounds__(256) void gat_agg_r3(const unsigned short* __restrict__ Hm,
    const float* __restrict__ als, const float* __restrict__ ald,
    const int* __restrict__ offs, const int* __restrict__ csrc,
    const float* __restrict__ bconv, unsigned short* __restrict__ Xout)
{
  const int wv = threadIdx.x >> 6, lane = threadIdx.x & 63;
  const int node = blockIdx.x * 4 + wv;
  const int hd = lane >> 3;
  const float aldv = ald[node * NH + hd];
  const int e0 = offs[node], e1 = offs[node + 1];
  float m = -1e30f, z = 0.f;
  for (int e = e0; e < e1; e++) {
    const int s = csrc[e];
    float lg = als[s * NH + hd] + aldv;
    lg = lg > 0.f ? lg : 0.2f * lg;
    const float mn = fmaxf(m, lg);
    z = z * __expf(m - mn) + __expf(lg - mn);
    m = mn;
  }
  const float zinv = 1.f / (z + 1e-16f);
  float acc[8] = {};
  for (int e = e0; e < e1; e++) {
    const int s = csrc[e];
    float lg = als[s * NH + hd] + aldv;
    lg = lg > 0.f ? lg : 0.2f * lg;
    const float w = __expf(lg - m) * zinv;
    const uint4 hv = *(const uint4*)&Hm[(size_t)s * DIM + lane * 8];
    const unsigned int* hp = (const unsigned int*)&hv;
    #pragma unroll
    for (int j = 0; j < 4; j++) {
      acc[2*j]   += w * bf2f((unsigned short)(hp[j] & 0xffffu));
      acc[2*j+1] += w * bf2f((unsigned short)(hp[j] >> 16));
    }
  }
  const float4 bA = ((const float4*)(bconv + (size_t)lane * 8))[0];
  const float4 bB = ((const float4*)(bconv + (size_t)lane * 8))[1];
  const float barr[8] = {bA.x, bA.y, bA.z, bA.w, bB.x, bB.y, bB.z, bB.w};
  unsigned int ov[4];
  #pragma unroll
  for (int j = 0; j < 4; j++) {
    ov[j] = (unsigned int)f2bf(acc[2*j] + barr[2*j])
          | ((unsigned int)f2bf(acc[2*j+1] + barr[2*j+1]) << 16);
  }
  *(uint4*)&Xout[(size_t)node * DIM + lane * 8] = *(const uint4*)ov;
}

// ---------------- BatchNorm ----------------
__global__ void zero_sums_r3(float* __restrict__ sums) {
  const int t = threadIdx.x;   // 256
  sums[t] = 0.f; sums[256 + t] = 0.f; sums[512 + t] = 0.f; sums[768 + t] = 0.f;
}
__global__ __launch_bounds__(256) void bn_stats_r3(const unsigned short* __restrict__ X, float* __restrict__ sums)
{
  const int t = threadIdx.x;
  const int c0 = t * 2;
  float s0 = 0.f, s1 = 0.f, q0 = 0.f, q1 = 0.f;
  for (int r = blockIdx.x; r < N_NODES; r += gridDim.x) {
    const unsigned int u = *(const unsigned int*)&X[(size_t)r * DIM + c0];
    const float a = bf2f((unsigned short)(u & 0xffffu));
    const float b = bf2f((unsigned short)(u >> 16));
    s0 += a; q0 += a * a; s1 += b; q1 += b * b;
  }
  atomicAdd(&sums[c0], s0);
  atomicAdd(&sums[c0 + 1], s1);
  atomicAdd(&sums[512 + c0], q0);
  atomicAdd(&sums[512 + c0 + 1], q1);
}
__global__ void bn_finalize_r3(const float* __restrict__ sums, const float* __restrict__ gamma,
                               const float* __restrict__ beta,
                               float* __restrict__ scale, float* __restrict__ shift)
{
  const int c = threadIdx.x;   // 512
  const float inv = 1.0f / (float)N_NODES;
  const float mean = sums[c] * inv;
  float var = sums[512 + c] * inv - mean * mean;
  var = fmaxf(var, 0.f);
  const float rs = rsqrtf(var + 1e-5f);
  const float sc = gamma[c] * rs;
  scale[c] = sc;
  shift[c] = beta[c] - mean * sc;
}
__global__ __launch_bounds__(256) void bn_apply_r3(unsigned short* __restrict__ X,
    const float* __restrict__ scale, const float* __restrict__ shift)
{
  const size_t i = ((size_t)blockIdx.x * 256 + threadIdx.x) * 8;
  const int c = (int)(i & (DIM - 1));
  uint4 v = *(const uint4*)&X[i];
  unsigned int* vp = (unsigned int*)&v;
  unsigned int ov[4];
  #pragma unroll
  for (int j = 0; j < 4; j++) {
    const float a = bf2f((unsigned short)(vp[j] & 0xffffu));
    const float b = bf2f((unsigned short)(vp[j] >> 16));
    const float ya = fmaxf(0.f, a * scale[c + 2*j]     + shift[c + 2*j]);
    const float yb = fmaxf(0.f, b * scale[c + 2*j + 1] + shift[c + 2*j + 1]);
    ov[j] = (unsigned int)f2bf(ya) | ((unsigned int)f2bf(yb) << 16);
  }
  *(uint4*)&X[i] = *(const uint4*)ov;
}

// ---------------- final head: out[n] = X[n,:] . Wl + bl  (fp32 out) ----------------
__global__ __launch_bounds__(256) void final_head_r3(const unsigned short* __restrict__ X,
    const float* __restrict__ wl, const float* __restrict__ blp,
    float* __restrict__ out)
{
  const int wv = threadIdx.x >> 6, lane = threadIdx.x & 63;
  const int node = blockIdx.x * 4 + wv;
  const uint4 xv = *(const uint4*)&X[(size_t)node * DIM + lane * 8];
  const unsigned int* xp = (const unsigned int*)&xv;
  const float4 wA = ((const float4*)(wl + (size_t)lane * 8))[0];
  const float4 wB = ((const float4*)(wl + (size_t)lane * 8))[1];
  const float warr[8] = {wA.x, wA.y, wA.z, wA.w, wB.x, wB.y, wB.z, wB.w};
  float s = 0.f;
  #pragma unroll
  for (int i = 0; i < 4; i++) {
    s += bf2f((unsigned short)(xp[i] & 0xffffu)) * warr[2*i];
    s += bf2f((unsigned short)(xp[i] >> 16))     * warr[2*i + 1];
  }
  #pragma unroll
  for (int msk = 32; msk >= 1; msk >>= 1) s += __shfl_xor(s, msk, 64);
  if (lane == 0) out[node] = s + blp[0];
}

extern "C" void kernel_launch(void* const* d_in, const int* in_sizes, int n_in,
                              void* d_out, int out_size, void* d_ws, size_t ws_size,
                              hipStream_t stream)
{
  const float* x_in  = (const float*)d_in[0];
  const int*   ei    = (const int*)d_in[1];
  const float* Ws    = (const float*)d_in[2];
  const float* Asrc  = (const float*)d_in[3];
  const float* Adst  = (const float*)d_in[4];
  const float* Bconv = (const float*)d_in[5];
  const float* Gamma = (const float*)d_in[6];
  const float* Beta  = (const float*)d_in[7];
  const float* Wl    = (const float*)d_in[8];
  const float* bl    = (const float*)d_in[9];
  float* out = (float*)d_out;

  char* ws = (char*)d_ws;
  size_t off = 0;
  auto alloc = [&](size_t b) { char* p = ws + off; off += (b + 255) & ~(size_t)255; return p; };
  unsigned short* xbuf = (unsigned short*)alloc((size_t)N_NODES * DIM * 2);
  unsigned short* hbuf = (unsigned short*)alloc((size_t)N_NODES * DIM * 2);
  unsigned short* WT   = (unsigned short*)alloc((size_t)NLAYERS * DIM * DIM * 2);
  float* als   = (float*)alloc((size_t)N_NODES * NH * 4);
  float* ald   = (float*)alloc((size_t)N_NODES * NH * 4);
  int* eidx    = (int*)alloc((size_t)2 * NE * 4);
  int* counts  = (int*)alloc((size_t)N_NODES * 4);
  int* offs    = (int*)alloc(((size_t)N_NODES + 1) * 4);
  int* cursor  = (int*)alloc((size_t)N_NODES * 4);
  int* csrc    = (int*)alloc((size_t)ETOT * 4);
  float* sums  = (float*)alloc(1024 * 4);
  float* scale = (float*)alloc(512 * 4);
  float* shift = (float*)alloc(512 * 4);

  convert_x_r3<<<(N_NODES * DIM / 8) / 256, 256, 0, stream>>>(x_in, xbuf);
  transpose_w_r3<<<dim3(16, 16, 5), 256, 0, stream>>>(Ws, WT);
  repack_edges_r3<<<(2 * NE) / 256, 256, 0, stream>>>(ei, eidx);
  init_counts_r3<<<N_NODES / 256, 256, 0, stream>>>(counts);
  hist_dst_r3<<<NE / 256, 256, 0, stream>>>(eidx, counts);
  scan_kernel_r3<<<1, 1024, 0, stream>>>(counts, offs, cursor);
  scatter_edges_r3<<<ETOT / 256, 256, 0, stream>>>(eidx, cursor, csrc);

  const unsigned short* xcur = xbuf;
  for (int l = 0; l < NLAYERS; l++) {
    gemm_bt_r3<<<dim3(N_NODES / 128, DIM / 128), 256, 0, stream>>>(xcur, WT + (size_t)l * DIM * DIM, hbuf);
    attn_logits_r3<<<N_NODES / 4, 256, 0, stream>>>(hbuf, Asrc + l * NH * DHEAD, Adst + l * NH * DHEAD, als, ald);
    gat_agg_r3<<<N_NODES / 4, 256, 0, stream>>>(hbuf, als, ald, offs, csrc, Bconv + l * DIM, xbuf);
    zero_sums_r3<<<1, 256, 0, stream>>>(sums);
    bn_stats_r3<<<256, 256, 0, stream>>>(xbuf, sums);
    bn_finalize_r3<<<1, 512, 0, stream>>>(sums, Gamma + l * DIM, Beta + l * DIM, scale, shift);
    bn_apply_r3<<<(N_NODES * DIM / 8) / 256, 256, 0, stream>>>(xbuf, scale, shift);
    xcur = xbuf;
  }
  final_head_r3<<<N_NODES / 4, 256, 0, stream>>>(xbuf, Wl, bl, out);
}